// Round 6
// baseline (117.386 us; speedup 1.0000x reference)
//
#include <hip/hip_runtime.h>

// Problem constants (fixed by setup_inputs in the reference)
#define B_  8
#define T_  2048
#define D_  1024
#define H_  8
#define S_  128

// --------------------------------------------------------------------------
// K1: logits[row][h] = dot(feat[row,:], kw[h,:]) + kb[h]
// Shaped for memory-level parallelism: 4 rows per wave (acc[32] keeps VGPR
// pressure low so the compiler can keep ~12 loads in flight per chunk),
// kw fragments register-resident per 256-col chunk (8 float4), no LDS.
// Grid 1024 blocks x 4 waves -> 16 waves/CU; feat streams 64 MB once at
// HBM BW; kw refetch is 128 MB of L2 (overlapped). Value-compacting
// reduction: 5 steps over lane bits 0..4 leave lane l with value (l&31)
// summed over its 32-lane half; one shfl_xor(32) completes it. Lanes 0..31
// store 32 contiguous floats (rows row0..row0+3 x 8 heads).
// --------------------------------------------------------------------------
__global__ __launch_bounds__(256) void logits_kernel(
    const float* __restrict__ feat,    // [B*T, D]
    const float* __restrict__ kw,      // [H, D]
    const float* __restrict__ kb,      // [H]
    float* __restrict__ logits)        // [B*T, H]
{
    const int wave = threadIdx.x >> 6;
    const int lane = threadIdx.x & 63;
    const int row0 = (blockIdx.x * 4 + wave) * 4;   // 1024 blocks * 4 waves * 4 rows

    float acc[32];
#pragma unroll
    for (int j = 0; j < 32; ++j) acc[j] = 0.f;

#pragma unroll
    for (int c = 0; c < 4; ++c) {
        float4 kf[H_];
#pragma unroll
        for (int h = 0; h < H_; ++h)
            kf[h] = *(const float4*)(kw + h * D_ + c * 256 + lane * 4);
        float4 fv[4];
#pragma unroll
        for (int r = 0; r < 4; ++r)
            fv[r] = *(const float4*)(feat + (size_t)(row0 + r) * D_ + c * 256 + lane * 4);
#pragma unroll
        for (int r = 0; r < 4; ++r)
#pragma unroll
            for (int h = 0; h < H_; ++h)
                acc[r * 8 + h] += fv[r].x * kf[h].x + fv[r].y * kf[h].y
                                + fv[r].z * kf[h].z + fv[r].w * kf[h].w;
    }

    // Value-compacting reduce over lane bits 0..4 (16+8+4+2+1 = 31 shuffles)
#pragma unroll
    for (int s = 0; s < 5; ++s) {
        const int m = 1 << s;
        const bool hi = (lane >> s) & 1;
#pragma unroll
        for (int j = 0; j < (16 >> s); ++j) {
            float mine  = hi ? acc[2 * j + 1] : acc[2 * j];
            float other = hi ? acc[2 * j]     : acc[2 * j + 1];
            acc[j] = mine + __shfl_xor(other, m, 64);
        }
    }
    // acc[0] on lane l = value (l&31) summed over the 32 lanes sharing bit5
    acc[0] += __shfl_xor(acc[0], 32, 64);

    if (lane < 32)
        logits[(size_t)row0 * H_ + lane] = acc[0] + kb[lane & 7];
}

// --------------------------------------------------------------------------
// K2 (validated in R3): barrier-free, LDS-free span softmax + weighted pool.
// One wave per (b,s,quarter-of-D). Each wave redundantly computes the whole
// span softmax in registers (lane l holds logits t=4l..4l+3, t=i*8+h);
// per-head reductions are parity-preserving shfl_xor over {2,4,8,16,32}.
// Weights broadcast with 2 shuffles per span row. Rows i >= width carry
// weight exactly 0; rows begin..begin+31 always in-bounds (begin <= 2015).
// --------------------------------------------------------------------------
__global__ __launch_bounds__(256) void pool_kernel(
    const float* __restrict__ feat,    // [B*T, D]
    const int* __restrict__ begins,    // [B*S]
    const int* __restrict__ ends,      // [B*S]
    const float* __restrict__ logits,  // [B*T, H]
    float* __restrict__ out)           // [B*S, D]
{
    const int bs   = blockIdx.x;            // 0 .. B_*S_-1
    const int wv   = threadIdx.x >> 6;      // quarter of D (256 cols)
    const int lane = threadIdx.x & 63;
    const int b    = bs >> 7;               // / S_

    const int begin = begins[bs];
    const int width = ends[bs] - begin;     // 1..32
    const size_t row0 = (size_t)b * T_ + begin;

    float4 lv = *(const float4*)(logits + row0 * H_ + lane * 4);
    const int w8 = width * H_;
    float v0 = (4 * lane + 0 < w8) ? lv.x : -1e30f;
    float v1 = (4 * lane + 1 < w8) ? lv.y : -1e30f;
    float v2 = (4 * lane + 2 < w8) ? lv.z : -1e30f;
    float v3 = (4 * lane + 3 < w8) ? lv.w : -1e30f;

    float m0 = v0, m1 = v1, m2 = v2, m3 = v3;
#pragma unroll
    for (int off = 2; off <= 32; off <<= 1) {
        m0 = fmaxf(m0, __shfl_xor(m0, off, 64));
        m1 = fmaxf(m1, __shfl_xor(m1, off, 64));
        m2 = fmaxf(m2, __shfl_xor(m2, off, 64));
        m3 = fmaxf(m3, __shfl_xor(m3, off, 64));
    }

    float e0 = __expf(v0 - m0);             // masked -> exactly 0
    float e1 = __expf(v1 - m1);
    float e2 = __expf(v2 - m2);
    float e3 = __expf(v3 - m3);
    float s0 = e0, s1 = e1, s2 = e2, s3 = e3;
#pragma unroll
    for (int off = 2; off <= 32; off <<= 1) {
        s0 += __shfl_xor(s0, off, 64);
        s1 += __shfl_xor(s1, off, 64);
        s2 += __shfl_xor(s2, off, 64);
        s3 += __shfl_xor(s3, off, 64);
    }
    const float w0 = e0 / s0, w1 = e1 / s1, w2 = e2 / s2, w3 = e3 / s3;

    // weight w[i][hh] lives on lane 2i+p, element (wv&1)*2 + (lane>=32),
    // with p = wv>>1 (wave-uniform).
    const int p = wv >> 1;
    const float wlo = (wv & 1) ? w2 : w0;
    const float whi = (wv & 1) ? w3 : w1;
    const bool hiHalf = (lane >= 32);

    const int colbase = wv * 256 + lane * 4;
    const float* fbase = feat + row0 * D_ + colbase;

    float4 acc = make_float4(0.f, 0.f, 0.f, 0.f);
    const int nch = (width + 7) >> 3;       // 1..4 chunks of 8 rows
    for (int ch = 0; ch < nch; ++ch) {
#pragma unroll
        for (int k = 0; k < 8; ++k) {
            const int i = ch * 8 + k;
            const float t0 = __shfl(wlo, 2 * i + p, 64);
            const float t1 = __shfl(whi, 2 * i + p, 64);
            const float wt = hiHalf ? t1 : t0;
            const float4 fv = *(const float4*)(fbase + (size_t)i * D_);
            acc.x += wt * fv.x;
            acc.y += wt * fv.y;
            acc.z += wt * fv.z;
            acc.w += wt * fv.w;
        }
    }

    *(float4*)(out + (size_t)bs * D_ + colbase) = acc;
}

extern "C" void kernel_launch(void* const* d_in, const int* in_sizes, int n_in,
                              void* d_out, int out_size, void* d_ws, size_t ws_size,
                              hipStream_t stream) {
    const float* feat   = (const float*)d_in[0];   // features f32 [B,T,D]
    const int*   begins = (const int*)d_in[1];     // int32 [B,S]
    const int*   ends   = (const int*)d_in[2];     // int32 [B,S]
    const float* kw     = (const float*)d_in[3];   // key_w f32 [H,D]
    const float* kb     = (const float*)d_in[4];   // key_b f32 [H]
    float*       out    = (float*)d_out;           // f32 [B*S, D]
    float* logits = (float*)d_ws;                  // 16384*8*4 = 512 KB scratch

    logits_kernel<<<(B_ * T_) / 16, 256, 0, stream>>>(feat, kw, kb, logits);
    pool_kernel<<<B_ * S_, 256, 0, stream>>>(feat, begins, ends, logits, out);
}

// Round 7
// 113.104 us; speedup vs baseline: 1.0379x; 1.0379x over previous
//
#include <hip/hip_runtime.h>

// Problem constants (fixed by setup_inputs in the reference)
#define B_  8
#define T_  2048
#define D_  1024
#define H_  8
#define S_  128

// --------------------------------------------------------------------------
// K1: logits[row][h] = dot(feat[row,:], kw[h,:]) + kb[h]
// Max-occupancy / max-MLP shape: ONE row per wave, 1024-thread blocks
// (16 rows/block), kw staged once per block into 32 KB LDS.
//   - Occupancy: LDS 32 KB -> 5 blocks/CU; wave cap 32/CU -> 32 waves/CU.
//   - Each wave has exactly one HBM latency stop: its 4 independent float4
//     row loads (wave covers 1 KB per load -> perfect coalescing).
//   - kw fragments come from LDS (contiguous ds_read_b128, conflict-free;
//     2-way bank aliasing is free on gfx950).
//   - Reduction: 3 compaction steps over lane bits 0..2 (7 shuffles) leave
//     lane l with head (l&7) summed over its 8-lane group; 3 butterflies
//     over bits 3..5 finish. Lanes 0..7 store 8 contiguous floats.
// --------------------------------------------------------------------------
__global__ __launch_bounds__(1024) void logits_kernel(
    const float* __restrict__ feat,    // [B*T, D]
    const float* __restrict__ kw,      // [H, D]
    const float* __restrict__ kb,      // [H]
    float* __restrict__ logits)        // [B*T, H]
{
    const int wv   = threadIdx.x >> 6;      // 0..15
    const int lane = threadIdx.x & 63;
    const int row  = blockIdx.x * 16 + wv;  // 1024 blocks -> rows 0..16383

    __shared__ __align__(16) float kwl[H_ * D_];  // 32 KB staged key_w

    {   // stage kw: 1024 threads x 2 float4 (coalesced)
        const float4* src = (const float4*)kw;
        float4*       dst = (float4*)kwl;
        dst[threadIdx.x]        = src[threadIdx.x];
        dst[threadIdx.x + 1024] = src[threadIdx.x + 1024];
    }

    // Issue the row loads BEFORE the barrier: independent of LDS staging.
    const float* fr = feat + (size_t)row * D_;
    float4 fv0 = *(const float4*)(fr +   0 + lane * 4);
    float4 fv1 = *(const float4*)(fr + 256 + lane * 4);
    float4 fv2 = *(const float4*)(fr + 512 + lane * 4);
    float4 fv3 = *(const float4*)(fr + 768 + lane * 4);

    __syncthreads();

    float acc[H_];
#pragma unroll
    for (int h = 0; h < H_; ++h) {
        const float* kh = &kwl[h * D_ + lane * 4];
        float4 k0 = *(const float4*)(kh +   0);
        float4 k1 = *(const float4*)(kh + 256);
        float4 k2 = *(const float4*)(kh + 512);
        float4 k3 = *(const float4*)(kh + 768);
        acc[h] = fv0.x * k0.x + fv0.y * k0.y + fv0.z * k0.z + fv0.w * k0.w
               + fv1.x * k1.x + fv1.y * k1.y + fv1.z * k1.z + fv1.w * k1.w
               + fv2.x * k2.x + fv2.y * k2.y + fv2.z * k2.z + fv2.w * k2.w
               + fv3.x * k3.x + fv3.y * k3.y + fv3.z * k3.z + fv3.w * k3.w;
    }

    // Value-compacting reduce over lane bits 0..2 (4+2+1 = 7 shuffles)
#pragma unroll
    for (int s = 0; s < 3; ++s) {
        const int m = 1 << s;
        const bool hi = (lane >> s) & 1;
#pragma unroll
        for (int j = 0; j < (4 >> s); ++j) {
            float mine  = hi ? acc[2 * j + 1] : acc[2 * j];
            float other = hi ? acc[2 * j]     : acc[2 * j + 1];
            acc[j] = mine + __shfl_xor(other, m, 64);
        }
    }
    // acc[0] on lane l = head (l&7) summed over lanes sharing bits 3..5
    acc[0] += __shfl_xor(acc[0],  8, 64);
    acc[0] += __shfl_xor(acc[0], 16, 64);
    acc[0] += __shfl_xor(acc[0], 32, 64);

    if (lane < H_)
        logits[(size_t)row * H_ + lane] = acc[0] + kb[lane];
}

// --------------------------------------------------------------------------
// K2 (unchanged from R6 for clean attribution): barrier-free, LDS-free span
// softmax + weighted pool. One wave per (b,s,quarter-of-D). Lane l holds
// logits t=4l..4l+3 (t=i*8+h); parity-preserving shfl_xor reductions over
// {2,4,8,16,32}; weights broadcast with 2 shuffles per span row. Rows
// i >= width carry weight exactly 0; rows begin..begin+31 always in-bounds.
// --------------------------------------------------------------------------
__global__ __launch_bounds__(256) void pool_kernel(
    const float* __restrict__ feat,    // [B*T, D]
    const int* __restrict__ begins,    // [B*S]
    const int* __restrict__ ends,      // [B*S]
    const float* __restrict__ logits,  // [B*T, H]
    float* __restrict__ out)           // [B*S, D]
{
    const int bs   = blockIdx.x;            // 0 .. B_*S_-1
    const int wv   = threadIdx.x >> 6;      // quarter of D (256 cols)
    const int lane = threadIdx.x & 63;
    const int b    = bs >> 7;               // / S_

    const int begin = begins[bs];
    const int width = ends[bs] - begin;     // 1..32
    const size_t row0 = (size_t)b * T_ + begin;

    float4 lv = *(const float4*)(logits + row0 * H_ + lane * 4);
    const int w8 = width * H_;
    float v0 = (4 * lane + 0 < w8) ? lv.x : -1e30f;
    float v1 = (4 * lane + 1 < w8) ? lv.y : -1e30f;
    float v2 = (4 * lane + 2 < w8) ? lv.z : -1e30f;
    float v3 = (4 * lane + 3 < w8) ? lv.w : -1e30f;

    float m0 = v0, m1 = v1, m2 = v2, m3 = v3;
#pragma unroll
    for (int off = 2; off <= 32; off <<= 1) {
        m0 = fmaxf(m0, __shfl_xor(m0, off, 64));
        m1 = fmaxf(m1, __shfl_xor(m1, off, 64));
        m2 = fmaxf(m2, __shfl_xor(m2, off, 64));
        m3 = fmaxf(m3, __shfl_xor(m3, off, 64));
    }

    float e0 = __expf(v0 - m0);             // masked -> exactly 0
    float e1 = __expf(v1 - m1);
    float e2 = __expf(v2 - m2);
    float e3 = __expf(v3 - m3);
    float s0 = e0, s1 = e1, s2 = e2, s3 = e3;
#pragma unroll
    for (int off = 2; off <= 32; off <<= 1) {
        s0 += __shfl_xor(s0, off, 64);
        s1 += __shfl_xor(s1, off, 64);
        s2 += __shfl_xor(s2, off, 64);
        s3 += __shfl_xor(s3, off, 64);
    }
    const float w0 = e0 / s0, w1 = e1 / s1, w2 = e2 / s2, w3 = e3 / s3;

    const int p = wv >> 1;
    const float wlo = (wv & 1) ? w2 : w0;
    const float whi = (wv & 1) ? w3 : w1;
    const bool hiHalf = (lane >= 32);

    const int colbase = wv * 256 + lane * 4;
    const float* fbase = feat + row0 * D_ + colbase;

    float4 acc = make_float4(0.f, 0.f, 0.f, 0.f);
    const int nch = (width + 7) >> 3;       // 1..4 chunks of 8 rows
    for (int ch = 0; ch < nch; ++ch) {
#pragma unroll
        for (int k = 0; k < 8; ++k) {
            const int i = ch * 8 + k;
            const float t0 = __shfl(wlo, 2 * i + p, 64);
            const float t1 = __shfl(whi, 2 * i + p, 64);
            const float wt = hiHalf ? t1 : t0;
            const float4 fv = *(const float4*)(fbase + (size_t)i * D_);
            acc.x += wt * fv.x;
            acc.y += wt * fv.y;
            acc.z += wt * fv.z;
            acc.w += wt * fv.w;
        }
    }

    *(float4*)(out + (size_t)bs * D_ + colbase) = acc;
}

extern "C" void kernel_launch(void* const* d_in, const int* in_sizes, int n_in,
                              void* d_out, int out_size, void* d_ws, size_t ws_size,
                              hipStream_t stream) {
    const float* feat   = (const float*)d_in[0];   // features f32 [B,T,D]
    const int*   begins = (const int*)d_in[1];     // int32 [B,S]
    const int*   ends   = (const int*)d_in[2];     // int32 [B,S]
    const float* kw     = (const float*)d_in[3];   // key_w f32 [H,D]
    const float* kb     = (const float*)d_in[4];   // key_b f32 [H]
    float*       out    = (float*)d_out;           // f32 [B*S, D]
    float* logits = (float*)d_ws;                  // 16384*8*4 = 512 KB scratch

    logits_kernel<<<1024, 1024, 0, stream>>>(feat, kw, kb, logits);
    pool_kernel<<<B_ * S_, 256, 0, stream>>>(feat, begins, ends, logits, out);
}

// Round 8
// 109.408 us; speedup vs baseline: 1.0729x; 1.0338x over previous
//
#include <hip/hip_runtime.h>

// Problem constants (fixed by setup_inputs in the reference)
#define B_  8
#define T_  2048
#define D_  1024
#define H_  8
#define S_  128

// --------------------------------------------------------------------------
// K1 (frozen from R7 for attribution): logits[row][h] = dot(feat[row,:],
// kw[h,:]) + kb[h]. One row per wave, 1024-thread blocks, kw staged into
// 32 KB LDS; 32 waves/CU; one HBM stop per wave.
// --------------------------------------------------------------------------
__global__ __launch_bounds__(1024) void logits_kernel(
    const float* __restrict__ feat,    // [B*T, D]
    const float* __restrict__ kw,      // [H, D]
    const float* __restrict__ kb,      // [H]
    float* __restrict__ logits)        // [B*T, H]
{
    const int wv   = threadIdx.x >> 6;      // 0..15
    const int lane = threadIdx.x & 63;
    const int row  = blockIdx.x * 16 + wv;  // 1024 blocks -> rows 0..16383

    __shared__ __align__(16) float kwl[H_ * D_];  // 32 KB staged key_w

    {   // stage kw: 1024 threads x 2 float4 (coalesced)
        const float4* src = (const float4*)kw;
        float4*       dst = (float4*)kwl;
        dst[threadIdx.x]        = src[threadIdx.x];
        dst[threadIdx.x + 1024] = src[threadIdx.x + 1024];
    }

    // Row loads issued BEFORE the barrier (independent of LDS staging).
    const float* fr = feat + (size_t)row * D_;
    float4 fv0 = *(const float4*)(fr +   0 + lane * 4);
    float4 fv1 = *(const float4*)(fr + 256 + lane * 4);
    float4 fv2 = *(const float4*)(fr + 512 + lane * 4);
    float4 fv3 = *(const float4*)(fr + 768 + lane * 4);

    __syncthreads();

    float acc[H_];
#pragma unroll
    for (int h = 0; h < H_; ++h) {
        const float* kh = &kwl[h * D_ + lane * 4];
        float4 k0 = *(const float4*)(kh +   0);
        float4 k1 = *(const float4*)(kh + 256);
        float4 k2 = *(const float4*)(kh + 512);
        float4 k3 = *(const float4*)(kh + 768);
        acc[h] = fv0.x * k0.x + fv0.y * k0.y + fv0.z * k0.z + fv0.w * k0.w
               + fv1.x * k1.x + fv1.y * k1.y + fv1.z * k1.z + fv1.w * k1.w
               + fv2.x * k2.x + fv2.y * k2.y + fv2.z * k2.z + fv2.w * k2.w
               + fv3.x * k3.x + fv3.y * k3.y + fv3.z * k3.z + fv3.w * k3.w;
    }

    // Value-compacting reduce over lane bits 0..2 (4+2+1 = 7 shuffles)
#pragma unroll
    for (int s = 0; s < 3; ++s) {
        const int m = 1 << s;
        const bool hi = (lane >> s) & 1;
#pragma unroll
        for (int j = 0; j < (4 >> s); ++j) {
            float mine  = hi ? acc[2 * j + 1] : acc[2 * j];
            float other = hi ? acc[2 * j]     : acc[2 * j + 1];
            acc[j] = mine + __shfl_xor(other, m, 64);
        }
    }
    acc[0] += __shfl_xor(acc[0],  8, 64);
    acc[0] += __shfl_xor(acc[0], 16, 64);
    acc[0] += __shfl_xor(acc[0], 32, 64);

    if (lane < H_)
        logits[(size_t)row * H_ + lane] = acc[0] + kb[lane];
}

// --------------------------------------------------------------------------
// K2 (rebuilt for memory-level parallelism): one block per (span, quarter).
// 4096 blocks x 256 threads -> 8 blocks/CU, 32 waves/CU.
//   - Each wave w handles span rows 8w..8w+7 for the block's 256 columns;
//     its 8 independent float4 loads are issued BEFORE the barrier (one
//     latency stop, overlapped across 8 resident blocks/CU).
//   - Wave 0 concurrently runs the proven register softmax over the span's
//     logit slab (lane l holds t=4l..4l+3, t=i*8+h; parity-preserving
//     shfl_xor over {2,4,8,16,32}; t>=width*8 masked to -1e30 -> weight
//     exactly 0) and writes all 256 weights to LDS.
//   - After the barrier, weights are read from LDS as half-wave broadcasts
//     (2 distinct addresses per wave -> conflict-free). NO dynamic shuffles.
//   - Inactive waves (8w >= width) contribute zero partials; 4 partials
//     reduce through a 4 KB LDS slab; wave 0 stores 1 KB coalesced.
// Rows begin..begin+31 are always in-bounds (begin <= 2015).
// --------------------------------------------------------------------------
__global__ __launch_bounds__(256) void pool_kernel(
    const float* __restrict__ feat,    // [B*T, D]
    const int* __restrict__ begins,    // [B*S]
    const int* __restrict__ ends,      // [B*S]
    const float* __restrict__ logits,  // [B*T, H]
    float* __restrict__ out)           // [B*S, D]
{
    const int blk  = blockIdx.x;            // bs*4 + q
    const int bs   = blk >> 2;
    const int q    = blk & 3;
    const int wv   = threadIdx.x >> 6;      // row-chunk 0..3
    const int lane = threadIdx.x & 63;
    const int b    = bs >> 7;               // / S_

    const int begin = begins[bs];
    const int width = ends[bs] - begin;     // 1..32
    const size_t row0 = (size_t)b * T_ + begin;

    __shared__ __align__(16) float wslab[256];        // weights [i*8+h]
    __shared__ __align__(16) float pslab[4 * 256];    // per-wave partials

    // ---- issue this wave's span-row loads first (they don't need weights)
    const int colbase = q * 256 + lane * 4;
    const float* fbase = feat + row0 * D_ + colbase;
    const bool active = (wv * 8) < width;
    float4 fv[8];
    if (active) {
#pragma unroll
        for (int k = 0; k < 8; ++k)
            fv[k] = *(const float4*)(fbase + (size_t)(wv * 8 + k) * D_);
    }

    // ---- wave 0: span softmax -> wslab (loads above already in flight)
    if (wv == 0) {
        float4 lv = *(const float4*)(logits + row0 * H_ + lane * 4);
        const int w8 = width * H_;
        float v0 = (4 * lane + 0 < w8) ? lv.x : -1e30f;
        float v1 = (4 * lane + 1 < w8) ? lv.y : -1e30f;
        float v2 = (4 * lane + 2 < w8) ? lv.z : -1e30f;
        float v3 = (4 * lane + 3 < w8) ? lv.w : -1e30f;

        float m0 = v0, m1 = v1, m2 = v2, m3 = v3;
#pragma unroll
        for (int off = 2; off <= 32; off <<= 1) {
            m0 = fmaxf(m0, __shfl_xor(m0, off, 64));
            m1 = fmaxf(m1, __shfl_xor(m1, off, 64));
            m2 = fmaxf(m2, __shfl_xor(m2, off, 64));
            m3 = fmaxf(m3, __shfl_xor(m3, off, 64));
        }
        float e0 = __expf(v0 - m0);          // masked -> exactly 0
        float e1 = __expf(v1 - m1);
        float e2 = __expf(v2 - m2);
        float e3 = __expf(v3 - m3);
        float s0 = e0, s1 = e1, s2 = e2, s3 = e3;
#pragma unroll
        for (int off = 2; off <= 32; off <<= 1) {
            s0 += __shfl_xor(s0, off, 64);
            s1 += __shfl_xor(s1, off, 64);
            s2 += __shfl_xor(s2, off, 64);
            s3 += __shfl_xor(s3, off, 64);
        }
        *(float4*)&wslab[lane * 4] =
            make_float4(e0 / s0, e1 / s1, e2 / s2, e3 / s3);
    }
    __syncthreads();

    // ---- weighted accumulate (weights via LDS half-wave broadcast)
    float4 acc = make_float4(0.f, 0.f, 0.f, 0.f);
    if (active) {
        const int hoff = 2 * q + (lane >= 32 ? 1 : 0);  // head for my cols
#pragma unroll
        for (int k = 0; k < 8; ++k) {
            const float wt = wslab[(wv * 8 + k) * 8 + hoff];
            acc.x += wt * fv[k].x;
            acc.y += wt * fv[k].y;
            acc.z += wt * fv[k].z;
            acc.w += wt * fv[k].w;
        }
    }
    *(float4*)&pslab[wv * 256 + lane * 4] = acc;   // inactive waves write 0
    __syncthreads();

    // ---- wave 0: reduce 4 partials, store 1 KB coalesced
    if (wv == 0) {
        float4 r0 = *(const float4*)&pslab[0 * 256 + lane * 4];
        float4 r1 = *(const float4*)&pslab[1 * 256 + lane * 4];
        float4 r2 = *(const float4*)&pslab[2 * 256 + lane * 4];
        float4 r3 = *(const float4*)&pslab[3 * 256 + lane * 4];
        float4 o = make_float4(r0.x + r1.x + r2.x + r3.x,
                               r0.y + r1.y + r2.y + r3.y,
                               r0.z + r1.z + r2.z + r3.z,
                               r0.w + r1.w + r2.w + r3.w);
        *(float4*)(out + (size_t)bs * D_ + colbase) = o;
    }
}

extern "C" void kernel_launch(void* const* d_in, const int* in_sizes, int n_in,
                              void* d_out, int out_size, void* d_ws, size_t ws_size,
                              hipStream_t stream) {
    const float* feat   = (const float*)d_in[0];   // features f32 [B,T,D]
    const int*   begins = (const int*)d_in[1];     // int32 [B,S]
    const int*   ends   = (const int*)d_in[2];     // int32 [B,S]
    const float* kw     = (const float*)d_in[3];   // key_w f32 [H,D]
    const float* kb     = (const float*)d_in[4];   // key_b f32 [H]
    float*       out    = (float*)d_out;           // f32 [B*S, D]
    float* logits = (float*)d_ws;                  // 16384*8*4 = 512 KB scratch

    logits_kernel<<<1024, 1024, 0, stream>>>(feat, kw, kb, logits);
    pool_kernel<<<B_ * S_ * 4, 256, 0, stream>>>(feat, begins, ends, logits, out);
}